// Round 7
// baseline (918.754 us; speedup 1.0000x reference)
//
#include <hip/hip_runtime.h>
#include <hip/hip_bf16.h>

typedef float f32x4 __attribute__((ext_vector_type(4)));
typedef short s16x8 __attribute__((ext_vector_type(8)));
typedef unsigned int u32x4 __attribute__((ext_vector_type(4)));

#define F_IN 256
#define F_OUT 64
#define KSPLIT 13
#define PRELINES 1500000   // 192 MB of mask, 128B lines

static __device__ __forceinline__ short f2bf(float f){  // RTNE
  union { float f; unsigned u; } x; x.f = f;
  unsigned r = (x.u + 0x7FFFu + ((x.u >> 16) & 1u)) >> 16;
  return (short)r;
}

static __device__ __forceinline__ unsigned pack_rtne(float f0, float f1){
  return ((unsigned)(unsigned short)f2bf(f0)) | ((unsigned)(unsigned short)f2bf(f1) << 16);
}

// truncation pack (bias cancels in L2-normalize downstream of the mask GEMM)
static __device__ __forceinline__ unsigned pack_trunc(float f0, float f1){
  return (__float_as_uint(f0) >> 16) | (__float_as_uint(f1) & 0xFFFF0000u);
}

static __device__ __forceinline__ float bf_lo(unsigned u){ return __uint_as_float(u << 16); }
static __device__ __forceinline__ float bf_hi(unsigned u){ return __uint_as_float(u & 0xFFFF0000u); }

union FragU { u32x4 u; s16x8 s; };

// ---------------- grid barrier (monotonic counter, no reset race) ----------------

__global__ void init_kernel(unsigned* bar){ if (threadIdx.x == 0) bar[0] = 0u; }

static __device__ __forceinline__ void gridbar(unsigned* bar, int nb, int* phase){
  __syncthreads();
  if (threadIdx.x == 0){
    __threadfence();                       // release: L2 writeback (agent scope)
    atomicAdd(bar, 1u);
    unsigned need = (unsigned)(++(*phase)) * (unsigned)nb;
    while (atomicAdd(bar, 0u) < need) __builtin_amdgcn_s_sleep(8);
    __threadfence();                       // acquire: L1/L2 invalidate
  }
  __syncthreads();
}

// ---------------- sparse propagate hop (device fn) ----------------

static __device__ void gather_phase(const float* __restrict__ Yk,
    const unsigned* __restrict__ tinb, const int* __restrict__ offsets,
    const int* __restrict__ csr_row, const float* __restrict__ csr_norm,
    const float* __restrict__ selfnorm, unsigned* __restrict__ toutb,
    float* __restrict__ toutf, int n, int wantf, int NW){
  int wid = (threadIdx.x >> 6) & 3, lane = threadIdx.x & 63;
  for (int base = blockIdx.x * 4; base < n; base += NW * 4){
    int node = base + wid;
    if (node >= n) continue;
    int e0 = offsets[node], e1 = offsets[node + 1];
    float sn = selfnorm[node];
    unsigned t0 = tinb[(size_t)node * 64 + lane];
    float2 yk = ((const float2*)Yk)[(size_t)node * 64 + lane];
    float ax = yk.x + sn * bf_lo(t0);
    float ay = yk.y + sn * bf_hi(t0);
    int i = e0;
    for (; i + 4 <= e1; i += 4){
      int r0 = csr_row[i], r1 = csr_row[i+1], r2 = csr_row[i+2], r3 = csr_row[i+3];
      float w0 = csr_norm[i], w1 = csr_norm[i+1], w2 = csr_norm[i+2], w3 = csr_norm[i+3];
      unsigned v0 = tinb[(size_t)r0 * 64 + lane];
      unsigned v1 = tinb[(size_t)r1 * 64 + lane];
      unsigned v2 = tinb[(size_t)r2 * 64 + lane];
      unsigned v3 = tinb[(size_t)r3 * 64 + lane];
      ax += w0 * bf_lo(v0); ay += w0 * bf_hi(v0);
      ax += w1 * bf_lo(v1); ay += w1 * bf_hi(v1);
      ax += w2 * bf_lo(v2); ay += w2 * bf_hi(v2);
      ax += w3 * bf_lo(v3); ay += w3 * bf_hi(v3);
    }
    for (; i < e1; ++i){
      unsigned v = tinb[(size_t)csr_row[i] * 64 + lane];
      float w = csr_norm[i];
      ax += w * bf_lo(v); ay += w * bf_hi(v);
    }
    if (wantf){
      float2 r; r.x = ax; r.y = ay;
      ((float2*)toutf)[(size_t)node * 64 + lane] = r;
    } else {
      toutb[(size_t)node * 64 + lane] = pack_rtne(ax, ay);
    }
  }
}

// ---------------- persistent mega kernel: CSR + fgemm + 4 hops + relu/trans ----------------
// blocks [0,NW): workers through 12 phases; blocks [NW,NB): L3-warm prefetch of mask.

struct MegaArgs {
  const float* feat; const float* feat_a; const int* ei; const float* mask; const float* W;
  int* deg; int* counts; int* offs; int* cursors; float* dis; float* selfnorm;
  int* csr_row; float* csr_norm; short* WT; float* Yc; unsigned* t0bf;
  unsigned* tb0; unsigned* tb1; float* u1; float* emb; float* emb_a; short* embBT;
  int* partial; int* prefix; unsigned* bar; float* sink;
  int n; int E; int NW; int NP;
};

__global__ __launch_bounds__(256) void mega_kernel(MegaArgs a){
  __shared__ __align__(16) char smem[128 * 72 * 2];
  int* ilds = (int*)smem;
  short* slds = (short*)smem;
  const int tid = threadIdx.x;
  const int bid = blockIdx.x;
  const int n = a.n, E = a.E, NW = a.NW;
  const size_t sl128 = (size_t)n * 128;
  int phase = 0;

  if (bid >= NW){
    // ---- prefetch role: warm L3 with leading 192 MB of mask ----
    float s = 0.0f;
    size_t stride = (size_t)a.NP * 256;
    for (size_t li = (size_t)(bid - NW) * 256 + tid; li < (size_t)PRELINES; li += stride)
      s += a.mask[li * 32];
    a.sink[(size_t)(bid - NW) * 256 + tid] = s;
    return;
  }

  // W0: zero deg/counts + WT transpose-cast
  for (int i = bid * 256 + tid; i < n; i += NW * 256){ a.deg[i] = 0; a.counts[i] = 0; }
  for (int i = bid * 256 + tid; i < 5 * 64 * 256; i += NW * 256){
    int k = i & 255, c = (i >> 8) & 63, by = i >> 14;
    a.WT[i] = f2bf(a.W[(size_t)(by * 256 + k) * 64 + c]);
  }
  gridbar(a.bar, NW, &phase);

  // W1: histogram
  for (int e = bid * 256 + tid; e < E; e += NW * 256){
    int r = a.ei[e], c = a.ei[E + e];
    if (r != c) atomicAdd(&a.deg[r], 1);
    atomicAdd(&a.counts[c], 1);
  }
  gridbar(a.bar, NW, &phase);

  // W2: dis/selfnorm + per-chunk count sums (40 chunks x 256)
  for (int i = bid * 256 + tid; i < n; i += NW * 256){
    float d = (float)(a.deg[i] + 1);
    a.dis[i] = rsqrtf(d);
    a.selfnorm[i] = 1.0f / d;
  }
  if (bid < 40){
    int idx = bid * 256 + tid;
    int v = (idx < n) ? a.counts[idx] : 0;
    ilds[tid] = v; __syncthreads();
    for (int off = 128; off >= 1; off >>= 1){
      if (tid < off) ilds[tid] += ilds[tid + off];
      __syncthreads();
    }
    if (tid == 0) a.partial[bid] = ilds[0];
  }
  gridbar(a.bar, NW, &phase);

  // W3: chunk-prefix scan (serial, 40 values)
  if (bid == 0 && tid == 0){
    int run = 0;
    for (int j = 0; j < 40; ++j){ a.prefix[j] = run; run += a.partial[j]; }
    a.prefix[40] = run;
    a.offs[n] = run;
  }
  gridbar(a.bar, NW, &phase);

  // W4: intra-chunk scan -> offsets/cursors
  if (bid < 40){
    int idx = bid * 256 + tid;
    int v = (idx < n) ? a.counts[idx] : 0;
    ilds[tid] = v; __syncthreads();
    for (int off = 1; off < 256; off <<= 1){
      int add = (tid >= off) ? ilds[tid - off] : 0;
      __syncthreads();
      ilds[tid] += add;
      __syncthreads();
    }
    int excl = ilds[tid] - v + a.prefix[bid];
    if (idx < n){ a.offs[idx] = excl; a.cursors[idx] = excl; }
  }
  gridbar(a.bar, NW, &phase);

  // W5: CSR fill
  for (int e = bid * 256 + tid; e < E; e += NW * 256){
    int r = a.ei[e], c = a.ei[E + e];
    int pos = atomicAdd(&a.cursors[c], 1);
    a.csr_row[pos] = r;
    a.csr_norm[pos] = (r == c) ? 0.0f : a.dis[r] * a.dis[c];
  }
  gridbar(a.bar, NW, &phase);

  // W6: feature GEMM, per-wave 16-row tiles; item = side*625 + rowtile
  {
    int w = tid >> 6, l = tid & 63, lr = l & 15, g = l >> 4;
    int nitems = (n / 16) * 2;
    for (int item = bid * 4 + w; item < nitems; item += NW * 4){
      int bz = item / (n / 16), bx = item % (n / 16);
      const float* X = bz ? a.feat_a : a.feat;
      int row0 = bx * 16;
      const f32x4* ap = (const f32x4*)(X + (size_t)(row0 + lr) * F_IN + g * 8);
      s16x8 afr[8];
      #pragma unroll
      for (int it = 0; it < 8; ++it){
        f32x4 x0 = ap[it * 8], x1 = ap[it * 8 + 1];
        FragU af;
        af.u[0] = pack_rtne(x0[0], x0[1]); af.u[1] = pack_rtne(x0[2], x0[3]);
        af.u[2] = pack_rtne(x1[0], x1[1]); af.u[3] = pack_rtne(x1[2], x1[3]);
        afr[it] = af.s;
      }
      for (int by = 0; by < 5; ++by){
        f32x4 acc[4];
        #pragma unroll
        for (int ct = 0; ct < 4; ++ct) acc[ct] = (f32x4){0,0,0,0};
        #pragma unroll
        for (int it = 0; it < 8; ++it)
          #pragma unroll
          for (int ct = 0; ct < 4; ++ct){
            const s16x8* bp = (const s16x8*)(a.WT + ((size_t)by * 64 + ct * 16 + lr) * F_IN + g * 8);
            acc[ct] = __builtin_amdgcn_mfma_f32_16x16x32_bf16(afr[it], bp[it * 4], acc[ct], 0, 0, 0);
          }
        float* yp = a.Yc + (size_t)by * n * 128 + (size_t)bz * 64;
        short* tb = (short*)a.t0bf;
        #pragma unroll
        for (int ct = 0; ct < 4; ++ct)
          #pragma unroll
          for (int i = 0; i < 4; ++i){
            int grow = row0 + g * 4 + i;
            yp[(size_t)grow * 128 + ct * 16 + lr] = acc[ct][i];
            if (by == 4) tb[(size_t)grow * 128 + bz * 64 + ct * 16 + lr] = f2bf(acc[ct][i]);
          }
      }
    }
  }
  gridbar(a.bar, NW, &phase);

  // W7..W10: 4 propagation hops (Horner)
  gather_phase(a.Yc + 3 * sl128, a.t0bf, a.offs, a.csr_row, a.csr_norm, a.selfnorm, a.tb0, (float*)0, n, 0, NW);
  gridbar(a.bar, NW, &phase);
  gather_phase(a.Yc + 2 * sl128, a.tb0, a.offs, a.csr_row, a.csr_norm, a.selfnorm, a.tb1, (float*)0, n, 0, NW);
  gridbar(a.bar, NW, &phase);
  gather_phase(a.Yc + 1 * sl128, a.tb1, a.offs, a.csr_row, a.csr_norm, a.selfnorm, a.tb0, (float*)0, n, 0, NW);
  gridbar(a.bar, NW, &phase);
  gather_phase(a.Yc + 0 * sl128, a.tb0, a.offs, a.csr_row, a.csr_norm, a.selfnorm, (unsigned*)0, a.u1, n, 1, NW);
  gridbar(a.bar, NW, &phase);

  // W11: relu + split + LDS-transpose bf16 pack
  {
    int ntile = (n + 63) / 64;
    for (int tile = bid; tile < ntile; tile += NW){
      int node0 = tile * 64;
      int nl = tid >> 2;
      int f0 = (tid & 3) * 32;
      int node = node0 + nl;
      if (node < n){
        const f32x4* up = (const f32x4*)(a.u1 + (size_t)node * 128 + f0);
        float* dst = (f0 < 64) ? (a.emb + (size_t)node * 64 + f0)
                               : (a.emb_a + (size_t)node * 64 + (f0 - 64));
        #pragma unroll
        for (int j4 = 0; j4 < 8; ++j4){
          f32x4 v = up[j4];
          #pragma unroll
          for (int e = 0; e < 4; ++e){
            float x = v[e] > 0.0f ? v[e] : 0.0f;
            v[e] = x;
            slds[(f0 + j4 * 4 + e) * 72 + nl] = f2bf(x);
          }
          ((f32x4*)dst)[j4] = v;
        }
      }
      __syncthreads();
      int f = tid >> 1, c0 = (tid & 1) * 32;
      short* op = a.embBT + (size_t)f * n + node0 + c0;
      const short* lp = slds + f * 72 + c0;
      if (node0 + 64 <= n){
        #pragma unroll
        for (int j = 0; j < 4; ++j)
          *(s16x8*)(op + j * 8) = *(const s16x8*)(lp + j * 8);
      } else {
        for (int j = 0; j < 32; ++j)
          if (node0 + c0 + j < n) op[j] = lp[j];
      }
      __syncthreads();
    }
  }
}

// ---------------- readout GEMM: vsum[ks][n][128] partial = mask @ embBT^T ----------------
// global_load_lds double-buffered, counted-vmcnt pipeline, chunk-XOR swizzle.

__global__ __launch_bounds__(256, 4) void readout_kernel(const float* __restrict__ mask,
    const short* __restrict__ embBT, float* __restrict__ vsum, int n){
  __shared__ float Ab[2][64][32];
  __shared__ short Bb[2][128][32];
  int t = threadIdx.x;
  int w = t >> 6, l = t & 63, lr = l & 15, g = l >> 4;
  int row0 = blockIdx.x * 64;
  int ks = blockIdx.y;

  int steps_total = (n + 31) >> 5;               // 313
  int per = steps_total / KSPLIT, rem = steps_total % KSPLIT;
  int sbeg = ks * per + (ks < rem ? ks : rem);
  int scnt = per + (ks < rem ? 1 : 0);
  bool tail = ((sbeg + scnt) == steps_total) && ((n & 31) != 0);
  int nf = scnt - (tail ? 1 : 0);
  int kb0 = sbeg << 5;

  int arow = row0 + w * 16 + (l >> 3);
  int aswz = ((l & 7) ^ ((l >> 3) & 7)) << 2;
  const float* asrc0 = mask + (size_t)min(arow,     n - 1) * n + aswz;
  const float* asrc1 = mask + (size_t)min(arow + 8, n - 1) * n + aswz;
  int bcol = w * 32 + (l >> 2);
  int bswz = ((l & 3) ^ ((l >> 3) & 3)) << 3;
  const short* bsrc0 = embBT + (size_t)bcol * n + bswz;
  const short* bsrc1 = embBT + (size_t)(bcol + 16) * n + bswz;

  #define GLDS(gp, lp) __builtin_amdgcn_global_load_lds( \
      (const __attribute__((address_space(1))) void*)(const void*)(gp), \
      (__attribute__((address_space(3))) void*)(void*)(lp), 16, 0, 0)
  #define STAGE(kb, bi) do{ \
    GLDS(asrc0 + (kb), &Ab[bi][w * 16     ][0]); \
    GLDS(asrc1 + (kb), &Ab[bi][w * 16 +  8][0]); \
    GLDS(bsrc0 + (kb), &Bb[bi][w * 32     ][0]); \
    GLDS(bsrc1 + (kb), &Bb[bi][w * 32 + 16][0]); \
  }while(0)

  f32x4 acc[8];
  #pragma unroll
  for (int ct = 0; ct < 8; ++ct) acc[ct] = (f32x4){0,0,0,0};

  if (nf > 0) STAGE(kb0, 0);
  if (nf > 1) STAGE(kb0 + 32, 1);

  for (int s = 0; s < nf; ++s){
    if (s + 1 < nf) asm volatile("s_waitcnt vmcnt(4)" ::: "memory");
    else            asm volatile("s_waitcnt vmcnt(0)" ::: "memory");
    __builtin_amdgcn_s_barrier();
    int cur = s & 1;
    f32x4 x0 = *(const f32x4*)&Ab[cur][w * 16 + lr][((2 * g)     ^ (lr & 7)) << 2];
    f32x4 x1 = *(const f32x4*)&Ab[cur][w * 16 + lr][((2 * g + 1) ^ (lr & 7)) << 2];
    FragU af;
    af.u[0] = pack_trunc(x0[0], x0[1]); af.u[1] = pack_trunc(x0[2], x0[3]);
    af.u[2] = pack_trunc(x1[0], x1[1]); af.u[3] = pack_trunc(x1[2], x1[3]);
    #pragma unroll
    for (int ct = 0; ct < 8; ++ct){
      s16x8 bf = *(const s16x8*)&Bb[cur][ct * 16 + lr][(g ^ ((lr >> 1) & 3)) << 3];
      acc[ct] = __builtin_amdgcn_mfma_f32_16x16x32_bf16(af.s, bf, acc[ct], 0, 0, 0);
    }
    asm volatile("s_waitcnt lgkmcnt(0)" ::: "memory");
    __builtin_amdgcn_s_barrier();
    if (s + 2 < nf) STAGE(kb0 + (s + 2) * 32, cur);
  }
  #undef STAGE
  #undef GLDS

  if (tail){
    int kb = kb0 + nf * 32;
    int kleft = n - kb;
    FragU af; af.u = (u32x4){0,0,0,0};
    const s16x8 bz = {0,0,0,0,0,0,0,0};
    s16x8 bf[8];
    #pragma unroll
    for (int ct = 0; ct < 8; ++ct) bf[ct] = bz;
    int r = row0 + w * 16 + lr;
    if (g * 8 < kleft){
      if (r < n){
        const f32x4* p = (const f32x4*)(mask + (size_t)r * n + kb + g * 8);
        f32x4 r0 = p[0], r1 = p[1];
        af.u[0] = pack_trunc(r0[0], r0[1]); af.u[1] = pack_trunc(r0[2], r0[3]);
        af.u[2] = pack_trunc(r1[0], r1[1]); af.u[3] = pack_trunc(r1[2], r1[3]);
      }
      #pragma unroll
      for (int ct = 0; ct < 8; ++ct)
        bf[ct] = *(const s16x8*)(embBT + (size_t)(ct * 16 + lr) * n + kb + g * 8);
    }
    #pragma unroll
    for (int ct = 0; ct < 8; ++ct)
      acc[ct] = __builtin_amdgcn_mfma_f32_16x16x32_bf16(af.s, bf[ct], acc[ct], 0, 0, 0);
  }

  float* vs = vsum + (size_t)ks * n * 128;
  int rbase = row0 + w * 16;
  #pragma unroll
  for (int ct = 0; ct < 8; ++ct)
    #pragma unroll
    for (int i = 0; i < 4; ++i){
      int gr = rbase + g * 4 + i;
      if (gr < n) vs[(size_t)gr * 128 + ct * 16 + lr] = acc[ct][i];
    }
}

// ---------------- fused: g = sigmoid(v/||v||) (K-split sum) + bilinear discriminator ----------------

__global__ __launch_bounds__(256) void gnorm_disc_kernel(const float* __restrict__ vsum,
    const float* __restrict__ emb, const float* __restrict__ emb_a,
    const float* __restrict__ Wb, const float* __restrict__ bptr,
    float* __restrict__ ret, float* __restrict__ reta, int n){
  __shared__ float Wl[64][65];
  int t = threadIdx.x;
  for (int i = t; i < 4096; i += 256) Wl[i >> 6][i & 63] = Wb[i];
  __syncthreads();
  int wid = t >> 6, lane = t & 63;
  int node = blockIdx.x * 4 + wid;
  if (node >= n) return;

  size_t stride = (size_t)n * 128;
  float v1 = 0.0f, v2 = 0.0f;
  #pragma unroll
  for (int ks = 0; ks < KSPLIT; ++ks){
    v1 += vsum[ks * stride + (size_t)node * 128 + lane];
    v2 += vsum[ks * stride + (size_t)node * 128 + 64 + lane];
  }
  float s1 = v1 * v1, s2 = v2 * v2;
  for (int off = 32; off >= 1; off >>= 1){
    s1 += __shfl_xor(s1, off);
    s2 += __shfl_xor(s2, off);
  }
  float i1 = v1 / fmaxf(sqrtf(s1), 1e-12f);
  float i2 = v2 / fmaxf(sqrtf(s2), 1e-12f);
  float g1 = 1.0f / (1.0f + expf(-i1));
  float g2 = 1.0f / (1.0f + expf(-i2));

  float e1 = emb[(size_t)node * 64 + lane];
  float e2 = emb_a[(size_t)node * 64 + lane];
  float u1 = 0.0f, u2 = 0.0f;
  for (int e = 0; e < 64; ++e){
    float wv = Wl[lane][e];
    u1 += wv * __shfl(g1, e);
    u2 += wv * __shfl(g2, e);
  }
  float p1 = e1 * u1, p2 = e2 * u1, p3 = e2 * u2, p4 = e1 * u2;
  for (int off = 32; off >= 1; off >>= 1){
    p1 += __shfl_xor(p1, off); p2 += __shfl_xor(p2, off);
    p3 += __shfl_xor(p3, off); p4 += __shfl_xor(p4, off);
  }
  if (lane == 0){
    float b = bptr[0];
    ret[(size_t)node * 2 + 0]  = p1 + b;
    ret[(size_t)node * 2 + 1]  = p2 + b;
    reta[(size_t)node * 2 + 0] = p3 + b;
    reta[(size_t)node * 2 + 1] = p4 + b;
  }
}

// ---------------- launch ----------------

extern "C" void kernel_launch(void* const* d_in, const int* in_sizes, int n_in,
                              void* d_out, int out_size, void* d_ws, size_t ws_size,
                              hipStream_t stream) {
  const float* feat   = (const float*)d_in[0];
  const float* feat_a = (const float*)d_in[1];
  const int*   ei     = (const int*)d_in[2];
  const float* mask   = (const float*)d_in[3];
  const float* W      = (const float*)d_in[4];
  const float* Wb     = (const float*)d_in[5];
  const float* bsc    = (const float*)d_in[6];
  const int n = in_sizes[0] / F_IN;      // 10000
  const int E = in_sizes[2] / 2;         // 640000
  const size_t sl128 = (size_t)n * 128;

  float* out  = (float*)d_out;
  float* ret  = out + (size_t)n * F_OUT;
  float* reta = ret + (size_t)n * 2;

  char* wsb = (char*)d_ws;
  size_t off = 0;
  #define WSALLOC(ptr, T, cnt) T* ptr = (T*)(wsb + off); off = (off + sizeof(T)*(size_t)(cnt) + 255) & ~(size_t)255
  WSALLOC(deg, int, n);
  WSALLOC(counts, int, n);
  WSALLOC(offs, int, n + 1);
  WSALLOC(cursors, int, n);
  WSALLOC(dis, float, n);
  WSALLOC(selfnorm, float, n);
  WSALLOC(csr_row, int, E);
  WSALLOC(csr_norm, float, E);
  WSALLOC(WT, short, 5 * 64 * 256);
  WSALLOC(Yc, float, sl128 * 5);
  WSALLOC(t0bf, unsigned, (size_t)n * 64);
  WSALLOC(tb0, unsigned, (size_t)n * 64);
  WSALLOC(tb1, unsigned, (size_t)n * 64);
  WSALLOC(u1, float, sl128);
  WSALLOC(emb_a, float, (size_t)n * F_OUT);
  WSALLOC(embBT, short, (size_t)128 * n);
  WSALLOC(vsum, float, sl128 * KSPLIT);
  WSALLOC(partial, int, 64);
  WSALLOC(prefix, int, 64);
  WSALLOC(bar, unsigned, 64);
  WSALLOC(sink, float, (size_t)2048 * 256);
  (void)ws_size; (void)n_in; (void)out_size;

  int occ = 0;
  hipOccupancyMaxActiveBlocksPerMultiprocessor(&occ, mega_kernel, 256, 0);
  if (occ < 1) occ = 1;
  if (occ > 8) occ = 8;
  int NB = occ * 256;                 // co-resident persistent grid (256 CUs)
  int NP = NB / 4;                    // prefetchers
  int NW = NB - NP;                   // workers (>= 192 >= 40 needed by scan)

  MegaArgs a;
  a.feat = feat; a.feat_a = feat_a; a.ei = ei; a.mask = mask; a.W = W;
  a.deg = deg; a.counts = counts; a.offs = offs; a.cursors = cursors;
  a.dis = dis; a.selfnorm = selfnorm; a.csr_row = csr_row; a.csr_norm = csr_norm;
  a.WT = WT; a.Yc = Yc; a.t0bf = t0bf; a.tb0 = tb0; a.tb1 = tb1; a.u1 = u1;
  a.emb = out; a.emb_a = emb_a; a.embBT = embBT;
  a.partial = partial; a.prefix = prefix; a.bar = bar; a.sink = sink;
  a.n = n; a.E = E; a.NW = NW; a.NP = NP;

  init_kernel<<<1, 64, 0, stream>>>(bar);
  mega_kernel<<<NB, 256, 0, stream>>>(a);
  readout_kernel<<<dim3((n + 63) / 64, KSPLIT), 256, 0, stream>>>(mask, embBT, vsum, n);
  gnorm_disc_kernel<<<(n + 3) / 4, 256, 0, stream>>>(vsum, out, emb_a, Wb, bsc, ret, reta, n);
}

// Round 8
// 427.156 us; speedup vs baseline: 2.1509x; 2.1509x over previous
//
#include <hip/hip_runtime.h>
#include <hip/hip_bf16.h>
#include <hip/hip_fp16.h>

typedef float f32x4 __attribute__((ext_vector_type(4)));
typedef short s16x8 __attribute__((ext_vector_type(8)));
typedef unsigned int u32x4 __attribute__((ext_vector_type(4)));

#define F_IN 256
#define F_OUT 64
#define KSPLIT 13

static __device__ __forceinline__ short f2bf(float f){  // RTNE
  union { float f; unsigned u; } x; x.f = f;
  unsigned r = (x.u + 0x7FFFu + ((x.u >> 16) & 1u)) >> 16;
  return (short)r;
}

static __device__ __forceinline__ unsigned pack_rtne(float f0, float f1){
  return ((unsigned)(unsigned short)f2bf(f0)) | ((unsigned)(unsigned short)f2bf(f1) << 16);
}

// truncation pack (bias cancels in L2-normalize downstream of the mask GEMM)
static __device__ __forceinline__ unsigned pack_trunc(float f0, float f1){
  return (__float_as_uint(f0) >> 16) | (__float_as_uint(f1) & 0xFFFF0000u);
}

static __device__ __forceinline__ float bf_lo(unsigned u){ return __uint_as_float(u << 16); }
static __device__ __forceinline__ float bf_hi(unsigned u){ return __uint_as_float(u & 0xFFFF0000u); }
static __device__ __forceinline__ float h16(unsigned u){   // fp16 in high16 -> f32
  return __half2float(__ushort_as_half((unsigned short)(u >> 16)));
}

union FragU { u32x4 u; s16x8 s; };

// ---------------- WT transpose-cast + zero deg/counts (replaces 2 memsets) ----------------

__global__ void wt_zero_kernel(const float* __restrict__ W, short* __restrict__ WT,
                               int* __restrict__ deg, int* __restrict__ counts, int n){
  int idx = blockIdx.x * blockDim.x + threadIdx.x;
  if (idx < n){ deg[idx] = 0; counts[idx] = 0; }
  if (idx < 5 * 64 * 256){
    int k = idx & 255, c = (idx >> 8) & 63, by = idx >> 14;
    WT[idx] = f2bf(W[(size_t)(by * 256 + k) * 64 + c]);
  }
}

// ---------------- degree / CSR build (self-edges dropped: weight 0 exactly) ----------------

__global__ void hist_kernel(const int* __restrict__ ei, int E, int* __restrict__ deg,
                            int* __restrict__ counts){
  int e = blockIdx.x * blockDim.x + threadIdx.x;
  if (e >= E) return;
  int r = ei[e], c = ei[E + e];
  if (r != c){ atomicAdd(&deg[r], 1); atomicAdd(&counts[c], 1); }
}

// scan of counts -> offsets/cursors, plus dis/selfnorm from deg (fused dis_kernel)
__global__ __launch_bounds__(1024) void scan_kernel(const int* __restrict__ counts,
                                                    const int* __restrict__ deg,
                                                    float* __restrict__ dis,
                                                    float* __restrict__ selfnorm,
                                                    int* __restrict__ offsets,
                                                    int* __restrict__ cursors, int n){
  const int C = 10;
  __shared__ int lds[1024];
  int tid = threadIdx.x;
  int base = tid * C;
  int s = 0;
  for (int i = 0; i < C; ++i){
    int idx = base + i;
    if (idx < n){
      s += counts[idx];
      float d = (float)(deg[idx] + 1);   // +1: appended self-loop
      dis[idx] = rsqrtf(d);
      selfnorm[idx] = 1.0f / d;
    }
  }
  lds[tid] = s; __syncthreads();
  for (int off = 1; off < 1024; off <<= 1){
    int add = (tid >= off) ? lds[tid - off] : 0;
    __syncthreads();
    lds[tid] += add;
    __syncthreads();
  }
  int run = lds[tid] - s;
  for (int i = 0; i < C; ++i){
    int idx = base + i;
    if (idx < n){ offsets[idx] = run; cursors[idx] = run; run += counts[idx]; }
  }
  if (tid == 1023) offsets[n] = lds[1023];
}

// packed CSR entry: row (u16) | fp16(norm) << 16
__global__ void fill_kernel(const int* __restrict__ ei, int E, const float* __restrict__ dis,
                            int* __restrict__ cursors, unsigned* __restrict__ csr){
  int e = blockIdx.x * blockDim.x + threadIdx.x;
  if (e >= E) return;
  int r = ei[e], c = ei[E + e];
  if (r == c) return;
  int pos = atomicAdd(&cursors[c], 1);
  unsigned h = (unsigned)__half_as_ushort(__float2half(dis[r] * dis[c]));
  csr[pos] = (unsigned)r | (h << 16);
}

// ---------------- feature GEMM: A-strip in regs, all 5 slabs per block ----------------
// Yc[by][M][128] f32 (z-half cols); also emits t0bf = bf16(Yc slab4). grid (M/16, 2).

__global__ __launch_bounds__(64) void fgemm_kernel(const float* __restrict__ X0,
                                                   const float* __restrict__ X1,
                                                   const short* __restrict__ WT,
                                                   float* __restrict__ Yc,
                                                   short* __restrict__ t0bf, int M){
  int bz = blockIdx.y;
  const float* X = bz ? X1 : X0;
  int l = threadIdx.x, lr = l & 15, g = l >> 4;
  int row0 = blockIdx.x * 16;
  const f32x4* ap = (const f32x4*)(X + (size_t)(row0 + lr) * F_IN + g * 8);
  s16x8 afr[8];
  #pragma unroll
  for (int it = 0; it < 8; ++it){
    f32x4 x0 = ap[it * 8], x1 = ap[it * 8 + 1];
    FragU af;
    af.u[0] = pack_rtne(x0[0], x0[1]); af.u[1] = pack_rtne(x0[2], x0[3]);
    af.u[2] = pack_rtne(x1[0], x1[1]); af.u[3] = pack_rtne(x1[2], x1[3]);
    afr[it] = af.s;
  }
  for (int by = 0; by < 5; ++by){
    f32x4 acc[4];
    #pragma unroll
    for (int ct = 0; ct < 4; ++ct) acc[ct] = (f32x4){0,0,0,0};
    const s16x8* bp[4];
    #pragma unroll
    for (int ct = 0; ct < 4; ++ct)
      bp[ct] = (const s16x8*)(WT + ((size_t)by * 64 + ct * 16 + lr) * F_IN + g * 8);
    #pragma unroll
    for (int it = 0; it < 8; ++it)
      #pragma unroll
      for (int ct = 0; ct < 4; ++ct)
        acc[ct] = __builtin_amdgcn_mfma_f32_16x16x32_bf16(afr[it], bp[ct][it * 4], acc[ct], 0, 0, 0);
    float* yp = Yc + (size_t)by * M * 128 + (size_t)bz * 64;
    #pragma unroll
    for (int ct = 0; ct < 4; ++ct)
      #pragma unroll
      for (int i = 0; i < 4; ++i){
        int grow = row0 + g * 4 + i;
        yp[(size_t)grow * 128 + ct * 16 + lr] = acc[ct][i];
        if (by == 4) t0bf[(size_t)grow * 128 + bz * 64 + ct * 16 + lr] = f2bf(acc[ct][i]);
      }
  }
}

// ---------------- sparse propagate (bf16 messages, packed CSR): tout = Yk + A * tin ----------------

__global__ __launch_bounds__(256) void gather_kernel(const float* __restrict__ Yk,
    const unsigned* __restrict__ tinb, const int* __restrict__ offsets,
    const unsigned* __restrict__ csr, const float* __restrict__ selfnorm,
    unsigned* __restrict__ toutb, float* __restrict__ toutf, int n, int wantf){
  int wid = threadIdx.x >> 6, lane = threadIdx.x & 63;
  int node = blockIdx.x * 4 + wid;
  if (node >= n) return;
  int e0 = offsets[node], e1 = offsets[node + 1];
  float sn = selfnorm[node];
  unsigned t0 = tinb[(size_t)node * 64 + lane];
  float2 yk = ((const float2*)Yk)[(size_t)node * 64 + lane];
  float ax = yk.x + sn * bf_lo(t0);
  float ay = yk.y + sn * bf_hi(t0);
  int i = e0;
  for (; i + 4 <= e1; i += 4){
    unsigned q0 = csr[i], q1 = csr[i+1], q2 = csr[i+2], q3 = csr[i+3];
    float w0 = h16(q0), w1 = h16(q1), w2 = h16(q2), w3 = h16(q3);
    unsigned v0 = tinb[(size_t)(q0 & 0xFFFFu) * 64 + lane];
    unsigned v1 = tinb[(size_t)(q1 & 0xFFFFu) * 64 + lane];
    unsigned v2 = tinb[(size_t)(q2 & 0xFFFFu) * 64 + lane];
    unsigned v3 = tinb[(size_t)(q3 & 0xFFFFu) * 64 + lane];
    ax += w0 * bf_lo(v0); ay += w0 * bf_hi(v0);
    ax += w1 * bf_lo(v1); ay += w1 * bf_hi(v1);
    ax += w2 * bf_lo(v2); ay += w2 * bf_hi(v2);
    ax += w3 * bf_lo(v3); ay += w3 * bf_hi(v3);
  }
  for (; i < e1; ++i){
    unsigned q = csr[i];
    float w = h16(q);
    unsigned v = tinb[(size_t)(q & 0xFFFFu) * 64 + lane];
    ax += w * bf_lo(v); ay += w * bf_hi(v);
  }
  if (wantf){
    float2 r; r.x = ax; r.y = ay;
    ((float2*)toutf)[(size_t)node * 64 + lane] = r;
  } else {
    toutb[(size_t)node * 64 + lane] = pack_rtne(ax, ay);
  }
}

// ---------------- relu + split + LDS-transpose bf16 pack ----------------

__global__ __launch_bounds__(256) void relu_trans_kernel(const float* __restrict__ u,
    float* __restrict__ emb, float* __restrict__ emb_a, short* __restrict__ embBT, int n){
  __shared__ short lds[128 * 72];
  int t = threadIdx.x;
  int node0 = blockIdx.x * 64;
  int nl = t >> 2;
  int f0 = (t & 3) * 32;
  int node = node0 + nl;
  if (node < n){
    const f32x4* up = (const f32x4*)(u + (size_t)node * 128 + f0);
    float* dst = (f0 < 64) ? (emb + (size_t)node * 64 + f0)
                           : (emb_a + (size_t)node * 64 + (f0 - 64));
    #pragma unroll
    for (int j4 = 0; j4 < 8; ++j4){
      f32x4 v = up[j4];
      #pragma unroll
      for (int e = 0; e < 4; ++e){
        float x = v[e] > 0.0f ? v[e] : 0.0f;
        v[e] = x;
        lds[(f0 + j4 * 4 + e) * 72 + nl] = f2bf(x);
      }
      ((f32x4*)dst)[j4] = v;
    }
  }
  __syncthreads();
  int f = t >> 1, c0 = (t & 1) * 32;
  short* op = embBT + (size_t)f * n + node0 + c0;
  const short* lp = lds + f * 72 + c0;
  if (node0 + 64 <= n){
    #pragma unroll
    for (int j = 0; j < 4; ++j)
      *(s16x8*)(op + j * 8) = *(const s16x8*)(lp + j * 8);
  } else {
    for (int j = 0; j < 32; ++j)
      if (node0 + c0 + j < n) op[j] = lp[j];
  }
}

// ---------------- readout GEMM: vsum[ks][n][128] partial = mask @ embBT^T ----------------
// global_load_lds double-buffered, counted-vmcnt pipeline, chunk-XOR swizzle
// via pre-swizzled global source + swizzled ds_read (rule 21). Tile 64x128xBK32.

__global__ __launch_bounds__(256, 4) void readout_kernel(const float* __restrict__ mask,
    const short* __restrict__ embBT, float* __restrict__ vsum, int n){
  __shared__ float Ab[2][64][32];   // logical [row][k], chunk-swizzled physically
  __shared__ short Bb[2][128][32];
  int t = threadIdx.x;
  int w = t >> 6, l = t & 63, lr = l & 15, g = l >> 4;
  int row0 = blockIdx.x * 64;
  int ks = blockIdx.y;

  int steps_total = (n + 31) >> 5;               // 313
  int per = steps_total / KSPLIT, rem = steps_total % KSPLIT;
  int sbeg = ks * per + (ks < rem ? ks : rem);
  int scnt = per + (ks < rem ? 1 : 0);
  bool tail = ((sbeg + scnt) == steps_total) && ((n & 31) != 0);
  int nf = scnt - (tail ? 1 : 0);
  int kb0 = sbeg << 5;

  // staging sources: linear LDS dest (lane*16B), source chunk pre-XOR'd
  int arow = row0 + w * 16 + (l >> 3);
  int aswz = ((l & 7) ^ ((l >> 3) & 7)) << 2;                 // float offset
  const float* asrc0 = mask + (size_t)min(arow,     n - 1) * n + aswz;
  const float* asrc1 = mask + (size_t)min(arow + 8, n - 1) * n + aswz;
  int bcol = w * 32 + (l >> 2);
  int bswz = ((l & 3) ^ ((l >> 3) & 3)) << 3;                 // short offset
  const short* bsrc0 = embBT + (size_t)bcol * n + bswz;
  const short* bsrc1 = embBT + (size_t)(bcol + 16) * n + bswz;

  #define GLDS(gp, lp) __builtin_amdgcn_global_load_lds( \
      (const __attribute__((address_space(1))) void*)(const void*)(gp), \
      (__attribute__((address_space(3))) void*)(void*)(lp), 16, 0, 0)
  #define STAGE(kb, bi) do{ \
    GLDS(asrc0 + (kb), &Ab[bi][w * 16     ][0]); \
    GLDS(asrc1 + (kb), &Ab[bi][w * 16 +  8][0]); \
    GLDS(bsrc0 + (kb), &Bb[bi][w * 32     ][0]); \
    GLDS(bsrc1 + (kb), &Bb[bi][w * 32 + 16][0]); \
  }while(0)

  f32x4 acc[8];
  #pragma unroll
  for (int ct = 0; ct < 8; ++ct) acc[ct] = (f32x4){0,0,0,0};

  if (nf > 0) STAGE(kb0, 0);
  if (nf > 1) STAGE(kb0 + 32, 1);

  for (int s = 0; s < nf; ++s){
    if (s + 1 < nf) asm volatile("s_waitcnt vmcnt(4)" ::: "memory");
    else            asm volatile("s_waitcnt vmcnt(0)" ::: "memory");
    __builtin_amdgcn_s_barrier();
    int cur = s & 1;
    f32x4 x0 = *(const f32x4*)&Ab[cur][w * 16 + lr][((2 * g)     ^ (lr & 7)) << 2];
    f32x4 x1 = *(const f32x4*)&Ab[cur][w * 16 + lr][((2 * g + 1) ^ (lr & 7)) << 2];
    FragU af;
    af.u[0] = pack_trunc(x0[0], x0[1]); af.u[1] = pack_trunc(x0[2], x0[3]);
    af.u[2] = pack_trunc(x1[0], x1[1]); af.u[3] = pack_trunc(x1[2], x1[3]);
    #pragma unroll
    for (int ct = 0; ct < 8; ++ct){
      s16x8 bf = *(const s16x8*)&Bb[cur][ct * 16 + lr][(g ^ ((lr >> 1) & 3)) << 3];
      acc[ct] = __builtin_amdgcn_mfma_f32_16x16x32_bf16(af.s, bf, acc[ct], 0, 0, 0);
    }
    asm volatile("s_waitcnt lgkmcnt(0)" ::: "memory");
    __builtin_amdgcn_s_barrier();
    if (s + 2 < nf) STAGE(kb0 + (s + 2) * 32, cur);
  }
  #undef STAGE
  #undef GLDS

  if (tail){
    int kb = kb0 + nf * 32;
    int kleft = n - kb;                          // 16
    FragU af; af.u = (u32x4){0,0,0,0};
    const s16x8 bz = {0,0,0,0,0,0,0,0};
    s16x8 bf[8];
    #pragma unroll
    for (int ct = 0; ct < 8; ++ct) bf[ct] = bz;
    int r = row0 + w * 16 + lr;
    if (g * 8 < kleft){
      if (r < n){
        const f32x4* p = (const f32x4*)(mask + (size_t)r * n + kb + g * 8);
        f32x4 r0 = p[0], r1 = p[1];
        af.u[0] = pack_trunc(r0[0], r0[1]); af.u[1] = pack_trunc(r0[2], r0[3]);
        af.u[2] = pack_trunc(r1[0], r1[1]); af.u[3] = pack_trunc(r1[2], r1[3]);
      }
      #pragma unroll
      for (int ct = 0; ct < 8; ++ct)
        bf[ct] = *(const s16x8*)(embBT + (size_t)(ct * 16 + lr) * n + kb + g * 8);
    }
    #pragma unroll
    for (int ct = 0; ct < 8; ++ct)
      acc[ct] = __builtin_amdgcn_mfma_f32_16x16x32_bf16(af.s, bf[ct], acc[ct], 0, 0, 0);
  }

  float* vs = vsum + (size_t)ks * n * 128;
  int rbase = row0 + w * 16;
  #pragma unroll
  for (int ct = 0; ct < 8; ++ct)
    #pragma unroll
    for (int i = 0; i < 4; ++i){
      int gr = rbase + g * 4 + i;
      if (gr < n) vs[(size_t)gr * 128 + ct * 16 + lr] = acc[ct][i];
    }
}

// ---------------- fused: g = sigmoid(v/||v||) (K-split sum) + bilinear discriminator ----------------

__global__ __launch_bounds__(256) void gnorm_disc_kernel(const float* __restrict__ vsum,
    const float* __restrict__ emb, const float* __restrict__ emb_a,
    const float* __restrict__ Wb, const float* __restrict__ bptr,
    float* __restrict__ ret, float* __restrict__ reta, int n){
  __shared__ float Wl[64][65];
  int t = threadIdx.x;
  for (int i = t; i < 4096; i += 256) Wl[i >> 6][i & 63] = Wb[i];
  __syncthreads();
  int wid = t >> 6, lane = t & 63;
  int node = blockIdx.x * 4 + wid;
  if (node >= n) return;

  size_t stride = (size_t)n * 128;
  float v1 = 0.0f, v2 = 0.0f;
  #pragma unroll
  for (int ks = 0; ks < KSPLIT; ++ks){
    v1 += vsum[ks * stride + (size_t)node * 128 + lane];
    v2 += vsum[ks * stride + (size_t)node * 128 + 64 + lane];
  }
  float s1 = v1 * v1, s2 = v2 * v2;
  for (int off = 32; off >= 1; off >>= 1){
    s1 += __shfl_xor(s1, off);
    s2 += __shfl_xor(s2, off);
  }
  float i1 = v1 / fmaxf(sqrtf(s1), 1e-12f);
  float i2 = v2 / fmaxf(sqrtf(s2), 1e-12f);
  float g1 = 1.0f / (1.0f + expf(-i1));
  float g2 = 1.0f / (1.0f + expf(-i2));

  float e1 = emb[(size_t)node * 64 + lane];
  float e2 = emb_a[(size_t)node * 64 + lane];
  float u1 = 0.0f, u2 = 0.0f;
  for (int e = 0; e < 64; ++e){
    float wv = Wl[lane][e];
    u1 += wv * __shfl(g1, e);
    u2 += wv * __shfl(g2, e);
  }
  float p1 = e1 * u1, p2 = e2 * u1, p3 = e2 * u2, p4 = e1 * u2;
  for (int off = 32; off >= 1; off >>= 1){
    p1 += __shfl_xor(p1, off); p2 += __shfl_xor(p2, off);
    p3 += __shfl_xor(p3, off); p4 += __shfl_xor(p4, off);
  }
  if (lane == 0){
    float b = bptr[0];
    ret[(size_t)node * 2 + 0]  = p1 + b;
    ret[(size_t)node * 2 + 1]  = p2 + b;
    reta[(size_t)node * 2 + 0] = p3 + b;
    reta[(size_t)node * 2 + 1] = p4 + b;
  }
}

// ---------------- launch ----------------

extern "C" void kernel_launch(void* const* d_in, const int* in_sizes, int n_in,
                              void* d_out, int out_size, void* d_ws, size_t ws_size,
                              hipStream_t stream) {
  const float* feat   = (const float*)d_in[0];
  const float* feat_a = (const float*)d_in[1];
  const int*   ei     = (const int*)d_in[2];
  const float* mask   = (const float*)d_in[3];
  const float* W      = (const float*)d_in[4];
  const float* Wb     = (const float*)d_in[5];
  const float* bsc    = (const float*)d_in[6];
  const int n = in_sizes[0] / F_IN;      // 10000
  const int E = in_sizes[2] / 2;         // 640000
  const size_t sl128 = (size_t)n * 128;

  float* out  = (float*)d_out;
  float* ret  = out + (size_t)n * F_OUT;
  float* reta = ret + (size_t)n * 2;

  char* wsb = (char*)d_ws;
  size_t off = 0;
  #define WSALLOC(ptr, T, cnt) T* ptr = (T*)(wsb + off); off = (off + sizeof(T)*(size_t)(cnt) + 255) & ~(size_t)255
  WSALLOC(deg, int, n);
  WSALLOC(counts, int, n);
  WSALLOC(offs, int, n + 1);
  WSALLOC(cursors, int, n);
  WSALLOC(dis, float, n);
  WSALLOC(selfnorm, float, n);
  WSALLOC(csr, unsigned, E);
  WSALLOC(WT, short, 5 * 64 * 256);
  WSALLOC(Yc, float, sl128 * 5);
  WSALLOC(t0bf, unsigned, (size_t)n * 64);
  WSALLOC(tb0, unsigned, (size_t)n * 64);
  WSALLOC(tb1, unsigned, (size_t)n * 64);
  WSALLOC(u1, float, sl128);
  WSALLOC(emb_a, float, (size_t)n * F_OUT);
  WSALLOC(embBT, short, (size_t)128 * n);
  WSALLOC(vsum, float, sl128 * KSPLIT);
  (void)ws_size; (void)n_in; (void)out_size;

  int eb = (E + 255) / 256;
  wt_zero_kernel<<<(5 * 64 * 256 + 255) / 256, 256, 0, stream>>>(W, WT, deg, counts, n);
  hist_kernel<<<eb, 256, 0, stream>>>(ei, E, deg, counts);
  scan_kernel<<<1, 1024, 0, stream>>>(counts, deg, dis, selfnorm, offs, cursors, n);
  fill_kernel<<<eb, 256, 0, stream>>>(ei, E, dis, cursors, csr);

  fgemm_kernel<<<dim3(n / 16, 2), 64, 0, stream>>>(feat, feat_a, WT, Yc, (short*)t0bf, n);

  int gb = (n + 3) / 4;
  // Horner: u = Yc4(bf16); u = Yc3 + A u; ... ; u = Yc0 + A u (f32 final)
  gather_kernel<<<gb, 256, 0, stream>>>(Yc + 3 * sl128, t0bf, offs, csr, selfnorm, tb0, (float*)0, n, 0);
  gather_kernel<<<gb, 256, 0, stream>>>(Yc + 2 * sl128, tb0,  offs, csr, selfnorm, tb1, (float*)0, n, 0);
  gather_kernel<<<gb, 256, 0, stream>>>(Yc + 1 * sl128, tb1,  offs, csr, selfnorm, tb0, (float*)0, n, 0);
  gather_kernel<<<gb, 256, 0, stream>>>(Yc + 0 * sl128, tb0,  offs, csr, selfnorm, (unsigned*)0, u1, n, 1);
  relu_trans_kernel<<<(n + 63) / 64, 256, 0, stream>>>(u1, out, emb_a, embBT, n);

  readout_kernel<<<dim3((n + 63) / 64, KSPLIT), 256, 0, stream>>>(mask, embBT, vsum, n);
  gnorm_disc_kernel<<<gb, 256, 0, stream>>>(vsum, out, emb_a, Wb, bsc, ret, reta, n);
}

// Round 9
// 371.687 us; speedup vs baseline: 2.4718x; 1.1492x over previous
//
#include <hip/hip_runtime.h>
#include <hip/hip_bf16.h>
#include <hip/hip_fp16.h>

typedef float f32x4 __attribute__((ext_vector_type(4)));
typedef short s16x8 __attribute__((ext_vector_type(8)));
typedef unsigned int u32x4 __attribute__((ext_vector_type(4)));

#define F_IN 256
#define F_OUT 64
#define KSPLIT 13
#define HBLK 80

static __device__ __forceinline__ short f2bf(float f){  // RTNE
  union { float f; unsigned u; } x; x.f = f;
  unsigned r = (x.u + 0x7FFFu + ((x.u >> 16) & 1u)) >> 16;
  return (short)r;
}

static __device__ __forceinline__ unsigned pack_rtne(float f0, float f1){
  return ((unsigned)(unsigned short)f2bf(f0)) | ((unsigned)(unsigned short)f2bf(f1) << 16);
}

// truncation pack (bias cancels in L2-normalize downstream of the mask GEMM)
static __device__ __forceinline__ unsigned pack_trunc(float f0, float f1){
  return (__float_as_uint(f0) >> 16) | (__float_as_uint(f1) & 0xFFFF0000u);
}

static __device__ __forceinline__ float bf_lo(unsigned u){ return __uint_as_float(u << 16); }
static __device__ __forceinline__ float bf_hi(unsigned u){ return __uint_as_float(u & 0xFFFF0000u); }
static __device__ __forceinline__ float h16(unsigned u){   // fp16 in high16 -> f32
  return __half2float(__ushort_as_half((unsigned short)(u >> 16)));
}

union FragU { u32x4 u; s16x8 s; };

// ---------------- WT transpose-cast + zero deg/counts (replaces 2 memsets) ----------------

__global__ void wt_zero_kernel(const float* __restrict__ W, short* __restrict__ WT,
                               int* __restrict__ deg, int* __restrict__ counts, int n){
  int idx = blockIdx.x * blockDim.x + threadIdx.x;
  if (idx < n){ deg[idx] = 0; counts[idx] = 0; }
  if (idx < 5 * 64 * 256){
    int k = idx & 255, c = (idx >> 8) & 63, by = idx >> 14;
    WT[idx] = f2bf(W[(size_t)(by * 256 + k) * 64 + c]);
  }
}

// ---------------- histogram via privatized LDS bins (contention-free global flush) ----------------
// phase 1: cols -> counts; phase 2: rows -> deg. Self-edges dropped (weight would be 0).

__global__ __launch_bounds__(1024) void hist_kernel(const int* __restrict__ ei, int E,
                                                    int* __restrict__ deg,
                                                    int* __restrict__ counts, int n){
  __shared__ int bins[10240];   // 40 KB
  int tid = threadIdx.x;
  int per = (E + HBLK - 1) / HBLK;
  int e0 = blockIdx.x * per, e1 = min(E, e0 + per);

  for (int i = tid; i < n; i += 1024) bins[i] = 0;
  __syncthreads();
  for (int e = e0 + tid; e < e1; e += 1024){
    int r = ei[e], c = ei[E + e];
    if (r != c) atomicAdd(&bins[c], 1);
  }
  __syncthreads();
  for (int i = tid; i < n; i += 1024){ int v = bins[i]; if (v) atomicAdd(&counts[i], v); }
  __syncthreads();

  for (int i = tid; i < n; i += 1024) bins[i] = 0;
  __syncthreads();
  for (int e = e0 + tid; e < e1; e += 1024){
    int r = ei[e], c = ei[E + e];
    if (r != c) atomicAdd(&bins[r], 1);
  }
  __syncthreads();
  for (int i = tid; i < n; i += 1024){ int v = bins[i]; if (v) atomicAdd(&deg[i], v); }
}

// ---------------- scan (coalesced I/O via LDS staging) + dis/selfnorm ----------------

__global__ __launch_bounds__(1024) void scan_kernel(const int* __restrict__ counts,
                                                    const int* __restrict__ deg,
                                                    float* __restrict__ dis,
                                                    float* __restrict__ selfnorm,
                                                    int* __restrict__ offsets,
                                                    int* __restrict__ cursors, int n){
  const int C = 10;
  __shared__ int vals[10240];   // 40 KB
  __shared__ int wsum[1024];    //  4 KB
  int tid = threadIdx.x;
  for (int i = tid; i < 10240; i += 1024) vals[i] = (i < n) ? counts[i] : 0;
  for (int i = tid; i < n; i += 1024){
    float d = (float)(deg[i] + 1);   // +1: appended self-loop
    dis[i] = rsqrtf(d);
    selfnorm[i] = 1.0f / d;
  }
  __syncthreads();
  int base = tid * C;
  int s = 0;
  #pragma unroll
  for (int i = 0; i < C; ++i) s += vals[base + i];
  wsum[tid] = s; __syncthreads();
  for (int off = 1; off < 1024; off <<= 1){
    int add = (tid >= off) ? wsum[tid - off] : 0;
    __syncthreads();
    wsum[tid] += add;
    __syncthreads();
  }
  int run = wsum[tid] - s;
  #pragma unroll
  for (int i = 0; i < C; ++i){ int v = vals[base + i]; vals[base + i] = run; run += v; }
  __syncthreads();
  for (int i = tid; i < 10240; i += 1024)
    if (i < n){ offsets[i] = vals[i]; cursors[i] = vals[i]; }
  if (tid == 1023) offsets[n] = wsum[1023];
}

// packed CSR entry: row (u16) | fp16(norm) << 16
__global__ void fill_kernel(const int* __restrict__ ei, int E, const float* __restrict__ dis,
                            int* __restrict__ cursors, unsigned* __restrict__ csr){
  int e = blockIdx.x * blockDim.x + threadIdx.x;
  if (e >= E) return;
  int r = ei[e], c = ei[E + e];
  if (r == c) return;
  int pos = atomicAdd(&cursors[c], 1);
  unsigned h = (unsigned)__half_as_ushort(__float2half(dis[r] * dis[c]));
  csr[pos] = (unsigned)r | (h << 16);
}

// ---------------- feature GEMM: A-strip in regs, all 5 slabs per block ----------------
// Yc[by][M][128] f32 (z-half cols); also emits t0bf = bf16(Yc slab4). grid (M/16, 2).

__global__ __launch_bounds__(64) void fgemm_kernel(const float* __restrict__ X0,
                                                   const float* __restrict__ X1,
                                                   const short* __restrict__ WT,
                                                   float* __restrict__ Yc,
                                                   short* __restrict__ t0bf, int M){
  int bz = blockIdx.y;
  const float* X = bz ? X1 : X0;
  int l = threadIdx.x, lr = l & 15, g = l >> 4;
  int row0 = blockIdx.x * 16;
  const f32x4* ap = (const f32x4*)(X + (size_t)(row0 + lr) * F_IN + g * 8);
  s16x8 afr[8];
  #pragma unroll
  for (int it = 0; it < 8; ++it){
    f32x4 x0 = ap[it * 8], x1 = ap[it * 8 + 1];
    FragU af;
    af.u[0] = pack_rtne(x0[0], x0[1]); af.u[1] = pack_rtne(x0[2], x0[3]);
    af.u[2] = pack_rtne(x1[0], x1[1]); af.u[3] = pack_rtne(x1[2], x1[3]);
    afr[it] = af.s;
  }
  for (int by = 0; by < 5; ++by){
    f32x4 acc[4];
    #pragma unroll
    for (int ct = 0; ct < 4; ++ct) acc[ct] = (f32x4){0,0,0,0};
    const s16x8* bp[4];
    #pragma unroll
    for (int ct = 0; ct < 4; ++ct)
      bp[ct] = (const s16x8*)(WT + ((size_t)by * 64 + ct * 16 + lr) * F_IN + g * 8);
    #pragma unroll
    for (int it = 0; it < 8; ++it)
      #pragma unroll
      for (int ct = 0; ct < 4; ++ct)
        acc[ct] = __builtin_amdgcn_mfma_f32_16x16x32_bf16(afr[it], bp[ct][it * 4], acc[ct], 0, 0, 0);
    float* yp = Yc + (size_t)by * M * 128 + (size_t)bz * 64;
    #pragma unroll
    for (int ct = 0; ct < 4; ++ct)
      #pragma unroll
      for (int i = 0; i < 4; ++i){
        int grow = row0 + g * 4 + i;
        yp[(size_t)grow * 128 + ct * 16 + lr] = acc[ct][i];
        if (by == 4) t0bf[(size_t)grow * 128 + bz * 64 + ct * 16 + lr] = f2bf(acc[ct][i]);
      }
  }
}

// ---------------- sparse propagate (bf16 messages, packed CSR): tout = Yk + A * tin ----------------

__global__ __launch_bounds__(256) void gather_kernel(const float* __restrict__ Yk,
    const unsigned* __restrict__ tinb, const int* __restrict__ offsets,
    const unsigned* __restrict__ csr, const float* __restrict__ selfnorm,
    unsigned* __restrict__ toutb, float* __restrict__ toutf, int n, int wantf){
  int wid = threadIdx.x >> 6, lane = threadIdx.x & 63;
  int node = blockIdx.x * 4 + wid;
  if (node >= n) return;
  int e0 = offsets[node], e1 = offsets[node + 1];
  float sn = selfnorm[node];
  unsigned t0 = tinb[(size_t)node * 64 + lane];
  float2 yk = ((const float2*)Yk)[(size_t)node * 64 + lane];
  float ax = yk.x + sn * bf_lo(t0);
  float ay = yk.y + sn * bf_hi(t0);
  int i = e0;
  for (; i + 4 <= e1; i += 4){
    unsigned q0 = csr[i], q1 = csr[i+1], q2 = csr[i+2], q3 = csr[i+3];
    float w0 = h16(q0), w1 = h16(q1), w2 = h16(q2), w3 = h16(q3);
    unsigned v0 = tinb[(size_t)(q0 & 0xFFFFu) * 64 + lane];
    unsigned v1 = tinb[(size_t)(q1 & 0xFFFFu) * 64 + lane];
    unsigned v2 = tinb[(size_t)(q2 & 0xFFFFu) * 64 + lane];
    unsigned v3 = tinb[(size_t)(q3 & 0xFFFFu) * 64 + lane];
    ax += w0 * bf_lo(v0); ay += w0 * bf_hi(v0);
    ax += w1 * bf_lo(v1); ay += w1 * bf_hi(v1);
    ax += w2 * bf_lo(v2); ay += w2 * bf_hi(v2);
    ax += w3 * bf_lo(v3); ay += w3 * bf_hi(v3);
  }
  for (; i < e1; ++i){
    unsigned q = csr[i];
    float w = h16(q);
    unsigned v = tinb[(size_t)(q & 0xFFFFu) * 64 + lane];
    ax += w * bf_lo(v); ay += w * bf_hi(v);
  }
  if (wantf){
    float2 r; r.x = ax; r.y = ay;
    ((float2*)toutf)[(size_t)node * 64 + lane] = r;
  } else {
    toutb[(size_t)node * 64 + lane] = pack_rtne(ax, ay);
  }
}

// ---------------- relu + split + LDS-transpose bf16 pack ----------------

__global__ __launch_bounds__(256) void relu_trans_kernel(const float* __restrict__ u,
    float* __restrict__ emb, float* __restrict__ emb_a, short* __restrict__ embBT, int n){
  __shared__ short lds[128 * 72];
  int t = threadIdx.x;
  int node0 = blockIdx.x * 64;
  int nl = t >> 2;
  int f0 = (t & 3) * 32;
  int node = node0 + nl;
  if (node < n){
    const f32x4* up = (const f32x4*)(u + (size_t)node * 128 + f0);
    float* dst = (f0 < 64) ? (emb + (size_t)node * 64 + f0)
                           : (emb_a + (size_t)node * 64 + (f0 - 64));
    #pragma unroll
    for (int j4 = 0; j4 < 8; ++j4){
      f32x4 v = up[j4];
      #pragma unroll
      for (int e = 0; e < 4; ++e){
        float x = v[e] > 0.0f ? v[e] : 0.0f;
        v[e] = x;
        lds[(f0 + j4 * 4 + e) * 72 + nl] = f2bf(x);
      }
      ((f32x4*)dst)[j4] = v;
    }
  }
  __syncthreads();
  int f = t >> 1, c0 = (t & 1) * 32;
  short* op = embBT + (size_t)f * n + node0 + c0;
  const short* lp = lds + f * 72 + c0;
  if (node0 + 64 <= n){
    #pragma unroll
    for (int j = 0; j < 4; ++j)
      *(s16x8*)(op + j * 8) = *(const s16x8*)(lp + j * 8);
  } else {
    for (int j = 0; j < 32; ++j)
      if (node0 + c0 + j < n) op[j] = lp[j];
  }
}

// ---------------- readout GEMM: vsum[ks][n][128] partial = mask @ embBT^T ----------------
// global_load_lds double-buffered, counted-vmcnt pipeline, chunk-XOR swizzle
// via pre-swizzled global source + swizzled ds_read (rule 21). Tile 64x128xBK32.

__global__ __launch_bounds__(256, 4) void readout_kernel(const float* __restrict__ mask,
    const short* __restrict__ embBT, float* __restrict__ vsum, int n){
  __shared__ float Ab[2][64][32];   // logical [row][k], chunk-swizzled physically
  __shared__ short Bb[2][128][32];
  int t = threadIdx.x;
  int w = t >> 6, l = t & 63, lr = l & 15, g = l >> 4;
  int row0 = blockIdx.x * 64;
  int ks = blockIdx.y;

  int steps_total = (n + 31) >> 5;               // 313
  int per = steps_total / KSPLIT, rem = steps_total % KSPLIT;
  int sbeg = ks * per + (ks < rem ? ks : rem);
  int scnt = per + (ks < rem ? 1 : 0);
  bool tail = ((sbeg + scnt) == steps_total) && ((n & 31) != 0);
  int nf = scnt - (tail ? 1 : 0);
  int kb0 = sbeg << 5;

  // staging sources: linear LDS dest (lane*16B), source chunk pre-XOR'd
  int arow = row0 + w * 16 + (l >> 3);
  int aswz = ((l & 7) ^ ((l >> 3) & 7)) << 2;                 // float offset
  const float* asrc0 = mask + (size_t)min(arow,     n - 1) * n + aswz;
  const float* asrc1 = mask + (size_t)min(arow + 8, n - 1) * n + aswz;
  int bcol = w * 32 + (l >> 2);
  int bswz = ((l & 3) ^ ((l >> 3) & 3)) << 3;                 // short offset
  const short* bsrc0 = embBT + (size_t)bcol * n + bswz;
  const short* bsrc1 = embBT + (size_t)(bcol + 16) * n + bswz;

  #define GLDS(gp, lp) __builtin_amdgcn_global_load_lds( \
      (const __attribute__((address_space(1))) void*)(const void*)(gp), \
      (__attribute__((address_space(3))) void*)(void*)(lp), 16, 0, 0)
  #define STAGE(kb, bi) do{ \
    GLDS(asrc0 + (kb), &Ab[bi][w * 16     ][0]); \
    GLDS(asrc1 + (kb), &Ab[bi][w * 16 +  8][0]); \
    GLDS(bsrc0 + (kb), &Bb[bi][w * 32     ][0]); \
    GLDS(bsrc1 + (kb), &Bb[bi][w * 32 + 16][0]); \
  }while(0)

  f32x4 acc[8];
  #pragma unroll
  for (int ct = 0; ct < 8; ++ct) acc[ct] = (f32x4){0,0,0,0};

  if (nf > 0) STAGE(kb0, 0);
  if (nf > 1) STAGE(kb0 + 32, 1);

  for (int s = 0; s < nf; ++s){
    if (s + 1 < nf) asm volatile("s_waitcnt vmcnt(4)" ::: "memory");
    else            asm volatile("s_waitcnt vmcnt(0)" ::: "memory");
    __builtin_amdgcn_s_barrier();
    int cur = s & 1;
    f32x4 x0 = *(const f32x4*)&Ab[cur][w * 16 + lr][((2 * g)     ^ (lr & 7)) << 2];
    f32x4 x1 = *(const f32x4*)&Ab[cur][w * 16 + lr][((2 * g + 1) ^ (lr & 7)) << 2];
    FragU af;
    af.u[0] = pack_trunc(x0[0], x0[1]); af.u[1] = pack_trunc(x0[2], x0[3]);
    af.u[2] = pack_trunc(x1[0], x1[1]); af.u[3] = pack_trunc(x1[2], x1[3]);
    #pragma unroll
    for (int ct = 0; ct < 8; ++ct){
      s16x8 bf = *(const s16x8*)&Bb[cur][ct * 16 + lr][(g ^ ((lr >> 1) & 3)) << 3];
      acc[ct] = __builtin_amdgcn_mfma_f32_16x16x32_bf16(af.s, bf, acc[ct], 0, 0, 0);
    }
    asm volatile("s_waitcnt lgkmcnt(0)" ::: "memory");
    __builtin_amdgcn_s_barrier();
    if (s + 2 < nf) STAGE(kb0 + (s + 2) * 32, cur);
  }
  #undef STAGE
  #undef GLDS

  if (tail){
    int kb = kb0 + nf * 32;
    int kleft = n - kb;                          // 16
    FragU af; af.u = (u32x4){0,0,0,0};
    const s16x8 bz = {0,0,0,0,0,0,0,0};
    s16x8 bf[8];
    #pragma unroll
    for (int ct = 0; ct < 8; ++ct) bf[ct] = bz;
    int r = row0 + w * 16 + lr;
    if (g * 8 < kleft){
      if (r < n){
        const f32x4* p = (const f32x4*)(mask + (size_t)r * n + kb + g * 8);
        f32x4 r0 = p[0], r1 = p[1];
        af.u[0] = pack_trunc(r0[0], r0[1]); af.u[1] = pack_trunc(r0[2], r0[3]);
        af.u[2] = pack_trunc(r1[0], r1[1]); af.u[3] = pack_trunc(r1[2], r1[3]);
      }
      #pragma unroll
      for (int ct = 0; ct < 8; ++ct)
        bf[ct] = *(const s16x8*)(embBT + (size_t)(ct * 16 + lr) * n + kb + g * 8);
    }
    #pragma unroll
    for (int ct = 0; ct < 8; ++ct)
      acc[ct] = __builtin_amdgcn_mfma_f32_16x16x32_bf16(af.s, bf[ct], acc[ct], 0, 0, 0);
  }

  float* vs = vsum + (size_t)ks * n * 128;
  int rbase = row0 + w * 16;
  #pragma unroll
  for (int ct = 0; ct < 8; ++ct)
    #pragma unroll
    for (int i = 0; i < 4; ++i){
      int gr = rbase + g * 4 + i;
      if (gr < n) vs[(size_t)gr * 128 + ct * 16 + lr] = acc[ct][i];
    }
}

// ---------------- fused: g = sigmoid(v/||v||) (K-split sum) + bilinear discriminator ----------------

__global__ __launch_bounds__(256) void gnorm_disc_kernel(const float* __restrict__ vsum,
    const float* __restrict__ emb, const float* __restrict__ emb_a,
    const float* __restrict__ Wb, const float* __restrict__ bptr,
    float* __restrict__ ret, float* __restrict__ reta, int n){
  __shared__ float Wl[64][65];
  int t = threadIdx.x;
  for (int i = t; i < 4096; i += 256) Wl[i >> 6][i & 63] = Wb[i];
  __syncthreads();
  int wid = t >> 6, lane = t & 63;
  int node = blockIdx.x * 4 + wid;
  if (node >= n) return;

  size_t stride = (size_t)n * 128;
  float v1 = 0.0f, v2 = 0.0f;
  #pragma unroll
  for (int ks = 0; ks < KSPLIT; ++ks){
    v1 += vsum[ks * stride + (size_t)node * 128 + lane];
    v2 += vsum[ks * stride + (size_t)node * 128 + 64 + lane];
  }
  float s1 = v1 * v1, s2 = v2 * v2;
  for (int off = 32; off >= 1; off >>= 1){
    s1 += __shfl_xor(s1, off);
    s2 += __shfl_xor(s2, off);
  }
  float i1 = v1 / fmaxf(sqrtf(s1), 1e-12f);
  float i2 = v2 / fmaxf(sqrtf(s2), 1e-12f);
  float g1 = 1.0f / (1.0f + expf(-i1));
  float g2 = 1.0f / (1.0f + expf(-i2));

  float e1 = emb[(size_t)node * 64 + lane];
  float e2 = emb_a[(size_t)node * 64 + lane];
  float u1 = 0.0f, u2 = 0.0f;
  for (int e = 0; e < 64; ++e){
    float wv = Wl[lane][e];
    u1 += wv * __shfl(g1, e);
    u2 += wv * __shfl(g2, e);
  }
  float p1 = e1 * u1, p2 = e2 * u1, p3 = e2 * u2, p4 = e1 * u2;
  for (int off = 32; off >= 1; off >>= 1){
    p1 += __shfl_xor(p1, off); p2 += __shfl_xor(p2, off);
    p3 += __shfl_xor(p3, off); p4 += __shfl_xor(p4, off);
  }
  if (lane == 0){
    float b = bptr[0];
    ret[(size_t)node * 2 + 0]  = p1 + b;
    ret[(size_t)node * 2 + 1]  = p2 + b;
    reta[(size_t)node * 2 + 0] = p3 + b;
    reta[(size_t)node * 2 + 1] = p4 + b;
  }
}

// ---------------- launch ----------------

extern "C" void kernel_launch(void* const* d_in, const int* in_sizes, int n_in,
                              void* d_out, int out_size, void* d_ws, size_t ws_size,
                              hipStream_t stream) {
  const float* feat   = (const float*)d_in[0];
  const float* feat_a = (const float*)d_in[1];
  const int*   ei     = (const int*)d_in[2];
  const float* mask   = (const float*)d_in[3];
  const float* W      = (const float*)d_in[4];
  const float* Wb     = (const float*)d_in[5];
  const float* bsc    = (const float*)d_in[6];
  const int n = in_sizes[0] / F_IN;      // 10000
  const int E = in_sizes[2] / 2;         // 640000
  const size_t sl128 = (size_t)n * 128;

  float* out  = (float*)d_out;
  float* ret  = out + (size_t)n * F_OUT;
  float* reta = ret + (size_t)n * 2;

  char* wsb = (char*)d_ws;
  size_t off = 0;
  #define WSALLOC(ptr, T, cnt) T* ptr = (T*)(wsb + off); off = (off + sizeof(T)*(size_t)(cnt) + 255) & ~(size_t)255
  WSALLOC(deg, int, n);
  WSALLOC(counts, int, n);
  WSALLOC(offs, int, n + 1);
  WSALLOC(cursors, int, n);
  WSALLOC(dis, float, n);
  WSALLOC(selfnorm, float, n);
  WSALLOC(csr, unsigned, E);
  WSALLOC(WT, short, 5 * 64 * 256);
  WSALLOC(Yc, float, sl128 * 5);
  WSALLOC(t0bf, unsigned, (size_t)n * 64);
  WSALLOC(tb0, unsigned, (size_t)n * 64);
  WSALLOC(tb1, unsigned, (size_t)n * 64);
  WSALLOC(u1, float, sl128);
  WSALLOC(emb_a, float, (size_t)n * F_OUT);
  WSALLOC(embBT, short, (size_t)128 * n);
  WSALLOC(vsum, float, sl128 * KSPLIT);
  (void)ws_size; (void)n_in; (void)out_size;

  int eb = (E + 255) / 256;
  wt_zero_kernel<<<(5 * 64 * 256 + 255) / 256, 256, 0, stream>>>(W, WT, deg, counts, n);
  hist_kernel<<<HBLK, 1024, 0, stream>>>(ei, E, deg, counts, n);
  scan_kernel<<<1, 1024, 0, stream>>>(counts, deg, dis, selfnorm, offs, cursors, n);
  fill_kernel<<<eb, 256, 0, stream>>>(ei, E, dis, cursors, csr);

  fgemm_kernel<<<dim3(n / 16, 2), 64, 0, stream>>>(feat, feat_a, WT, Yc, (short*)t0bf, n);

  int gb = (n + 3) / 4;
  // Horner: u = Yc4(bf16); u = Yc3 + A u; ... ; u = Yc0 + A u (f32 final)
  gather_kernel<<<gb, 256, 0, stream>>>(Yc + 3 * sl128, t0bf, offs, csr, selfnorm, tb0, (float*)0, n, 0);
  gather_kernel<<<gb, 256, 0, stream>>>(Yc + 2 * sl128, tb0,  offs, csr, selfnorm, tb1, (float*)0, n, 0);
  gather_kernel<<<gb, 256, 0, stream>>>(Yc + 1 * sl128, tb1,  offs, csr, selfnorm, tb0, (float*)0, n, 0);
  gather_kernel<<<gb, 256, 0, stream>>>(Yc + 0 * sl128, tb0,  offs, csr, selfnorm, (unsigned*)0, u1, n, 1);
  relu_trans_kernel<<<(n + 63) / 64, 256, 0, stream>>>(u1, out, emb_a, embBT, n);

  readout_kernel<<<dim3((n + 63) / 64, KSPLIT), 256, 0, stream>>>(mask, embBT, vsum, n);
  gnorm_disc_kernel<<<gb, 256, 0, stream>>>(vsum, out, emb_a, Wb, bsc, ret, reta, n);
}

// Round 10
// 358.871 us; speedup vs baseline: 2.5601x; 1.0357x over previous
//
#include <hip/hip_runtime.h>
#include <hip/hip_bf16.h>
#include <hip/hip_fp16.h>

typedef float f32x4 __attribute__((ext_vector_type(4)));
typedef short s16x8 __attribute__((ext_vector_type(8)));
typedef unsigned int u32x4 __attribute__((ext_vector_type(4)));

#define F_IN 256
#define F_OUT 64
#define KSPLIT 13
#define HBLK 80

static __device__ __forceinline__ short f2bf(float f){  // RTNE
  union { float f; unsigned u; } x; x.f = f;
  unsigned r = (x.u + 0x7FFFu + ((x.u >> 16) & 1u)) >> 16;
  return (short)r;
}

static __device__ __forceinline__ unsigned pack_rtne(float f0, float f1){
  return ((unsigned)(unsigned short)f2bf(f0)) | ((unsigned)(unsigned short)f2bf(f1) << 16);
}

// truncation pack (bias cancels in L2-normalize downstream of the mask GEMM)
static __device__ __forceinline__ unsigned pack_trunc(float f0, float f1){
  return (__float_as_uint(f0) >> 16) | (__float_as_uint(f1) & 0xFFFF0000u);
}

static __device__ __forceinline__ float bf_lo(unsigned u){ return __uint_as_float(u << 16); }
static __device__ __forceinline__ float bf_hi(unsigned u){ return __uint_as_float(u & 0xFFFF0000u); }
static __device__ __forceinline__ float h16(unsigned u){   // fp16 in high16 -> f32
  return __half2float(__ushort_as_half((unsigned short)(u >> 16)));
}

union FragU { u32x4 u; s16x8 s; };

// ---------------- WT transpose-cast + zero deg/counts (replaces 2 memsets) ----------------

__global__ void wt_zero_kernel(const float* __restrict__ W, short* __restrict__ WT,
                               int* __restrict__ deg, int* __restrict__ counts, int n){
  int idx = blockIdx.x * blockDim.x + threadIdx.x;
  if (idx < n){ deg[idx] = 0; counts[idx] = 0; }
  if (idx < 5 * 64 * 256){
    int k = idx & 255, c = (idx >> 8) & 63, by = idx >> 14;
    WT[idx] = f2bf(W[(size_t)(by * 256 + k) * 64 + c]);
  }
}

// ---------------- histogram via privatized LDS bins; persists per-block col counts ----------------

__global__ __launch_bounds__(1024) void hist_kernel(const int* __restrict__ ei, int E,
                                                    int* __restrict__ deg,
                                                    int* __restrict__ counts,
                                                    int* __restrict__ blkcnt, int n){
  __shared__ int bins[10240];   // 40 KB
  int tid = threadIdx.x;
  int per = (E + HBLK - 1) / HBLK;
  int e0 = blockIdx.x * per, e1 = min(E, e0 + per);

  for (int i = tid; i < n; i += 1024) bins[i] = 0;
  __syncthreads();
  for (int e = e0 + tid; e < e1; e += 1024){
    int r = ei[e], c = ei[E + e];
    if (r != c) atomicAdd(&bins[c], 1);
  }
  __syncthreads();
  for (int i = tid; i < n; i += 1024){
    int v = bins[i];
    blkcnt[(size_t)blockIdx.x * n + i] = v;
    if (v) atomicAdd(&counts[i], v);
  }
  __syncthreads();

  for (int i = tid; i < n; i += 1024) bins[i] = 0;
  __syncthreads();
  for (int e = e0 + tid; e < e1; e += 1024){
    int r = ei[e], c = ei[E + e];
    if (r != c) atomicAdd(&bins[r], 1);
  }
  __syncthreads();
  for (int i = tid; i < n; i += 1024){ int v = bins[i]; if (v) atomicAdd(&deg[i], v); }
}

// ---------------- scan (coalesced I/O via LDS staging) + dis/selfnorm ----------------

__global__ __launch_bounds__(1024) void scan_kernel(const int* __restrict__ counts,
                                                    const int* __restrict__ deg,
                                                    float* __restrict__ dis,
                                                    float* __restrict__ selfnorm,
                                                    int* __restrict__ offsets, int n){
  const int C = 10;
  __shared__ int vals[10240];   // 40 KB
  __shared__ int wsum[1024];    //  4 KB
  int tid = threadIdx.x;
  for (int i = tid; i < 10240; i += 1024) vals[i] = (i < n) ? counts[i] : 0;
  for (int i = tid; i < n; i += 1024){
    float d = (float)(deg[i] + 1);   // +1: appended self-loop
    dis[i] = rsqrtf(d);
    selfnorm[i] = 1.0f / d;
  }
  __syncthreads();
  int base = tid * C;
  int s = 0;
  #pragma unroll
  for (int i = 0; i < C; ++i) s += vals[base + i];
  wsum[tid] = s; __syncthreads();
  for (int off = 1; off < 1024; off <<= 1){
    int add = (tid >= off) ? wsum[tid - off] : 0;
    __syncthreads();
    wsum[tid] += add;
    __syncthreads();
  }
  int run = wsum[tid] - s;
  #pragma unroll
  for (int i = 0; i < C; ++i){ int v = vals[base + i]; vals[base + i] = run; run += v; }
  __syncthreads();
  for (int i = tid; i < 10240; i += 1024)
    if (i < n) offsets[i] = vals[i];
  if (tid == 1023) offsets[n] = wsum[1023];
}

// ---------------- per-(block,bin) base positions: serial scan over 80 blocks ----------------

__global__ void blkbase_kernel(const int* __restrict__ offsets, const int* __restrict__ blkcnt,
                               int* __restrict__ blkbase, int n){
  int bin = blockIdx.x * blockDim.x + threadIdx.x;
  if (bin >= n) return;
  int run = offsets[bin];
  for (int blk = 0; blk < HBLK; ++blk){
    blkbase[(size_t)blk * n + bin] = run;
    run += blkcnt[(size_t)blk * n + bin];
  }
}

// ---------------- fill via LDS cursors (zero global atomics) ----------------
// packed CSR entry: row (u16) | fp16(norm) << 16. Edge ranges match hist_kernel.

__global__ __launch_bounds__(1024) void fill_kernel(const int* __restrict__ ei, int E,
                                                    const float* __restrict__ dis,
                                                    const int* __restrict__ blkbase,
                                                    unsigned* __restrict__ csr, int n){
  __shared__ int bins[10240];   // 40 KB
  int tid = threadIdx.x;
  int per = (E + HBLK - 1) / HBLK;
  int e0 = blockIdx.x * per, e1 = min(E, e0 + per);
  for (int i = tid; i < n; i += 1024) bins[i] = blkbase[(size_t)blockIdx.x * n + i];
  __syncthreads();
  for (int e = e0 + tid; e < e1; e += 1024){
    int r = ei[e], c = ei[E + e];
    if (r == c) continue;
    int pos = atomicAdd(&bins[c], 1);
    unsigned h = (unsigned)__half_as_ushort(__float2half(dis[r] * dis[c]));
    csr[pos] = (unsigned)r | (h << 16);
  }
}

// ---------------- feature GEMM: A-strip in regs, all 5 slabs per block ----------------
// Yc[by][M][128] f32 (z-half cols); also emits t0bf = bf16(Yc slab4). grid (M/16, 2).

__global__ __launch_bounds__(64) void fgemm_kernel(const float* __restrict__ X0,
                                                   const float* __restrict__ X1,
                                                   const short* __restrict__ WT,
                                                   float* __restrict__ Yc,
                                                   short* __restrict__ t0bf, int M){
  int bz = blockIdx.y;
  const float* X = bz ? X1 : X0;
  int l = threadIdx.x, lr = l & 15, g = l >> 4;
  int row0 = blockIdx.x * 16;
  const f32x4* ap = (const f32x4*)(X + (size_t)(row0 + lr) * F_IN + g * 8);
  s16x8 afr[8];
  #pragma unroll
  for (int it = 0; it < 8; ++it){
    f32x4 x0 = ap[it * 8], x1 = ap[it * 8 + 1];
    FragU af;
    af.u[0] = pack_rtne(x0[0], x0[1]); af.u[1] = pack_rtne(x0[2], x0[3]);
    af.u[2] = pack_rtne(x1[0], x1[1]); af.u[3] = pack_rtne(x1[2], x1[3]);
    afr[it] = af.s;
  }
  for (int by = 0; by < 5; ++by){
    f32x4 acc[4];
    #pragma unroll
    for (int ct = 0; ct < 4; ++ct) acc[ct] = (f32x4){0,0,0,0};
    const s16x8* bp[4];
    #pragma unroll
    for (int ct = 0; ct < 4; ++ct)
      bp[ct] = (const s16x8*)(WT + ((size_t)by * 64 + ct * 16 + lr) * F_IN + g * 8);
    #pragma unroll
    for (int it = 0; it < 8; ++it)
      #pragma unroll
      for (int ct = 0; ct < 4; ++ct)
        acc[ct] = __builtin_amdgcn_mfma_f32_16x16x32_bf16(afr[it], bp[ct][it * 4], acc[ct], 0, 0, 0);
    float* yp = Yc + (size_t)by * M * 128 + (size_t)bz * 64;
    #pragma unroll
    for (int ct = 0; ct < 4; ++ct)
      #pragma unroll
      for (int i = 0; i < 4; ++i){
        int grow = row0 + g * 4 + i;
        yp[(size_t)grow * 128 + ct * 16 + lr] = acc[ct][i];
        if (by == 4) t0bf[(size_t)grow * 128 + bz * 64 + ct * 16 + lr] = f2bf(acc[ct][i]);
      }
  }
}

// ---------------- sparse propagate (bf16 messages, packed CSR): tout = Yk + A * tin ----------------

__global__ __launch_bounds__(256) void gather_kernel(const float* __restrict__ Yk,
    const unsigned* __restrict__ tinb, const int* __restrict__ offsets,
    const unsigned* __restrict__ csr, const float* __restrict__ selfnorm,
    unsigned* __restrict__ toutb, float* __restrict__ toutf, int n, int wantf){
  int wid = threadIdx.x >> 6, lane = threadIdx.x & 63;
  int node = blockIdx.x * 4 + wid;
  if (node >= n) return;
  int e0 = offsets[node], e1 = offsets[node + 1];
  float sn = selfnorm[node];
  unsigned t0 = tinb[(size_t)node * 64 + lane];
  float2 yk = ((const float2*)Yk)[(size_t)node * 64 + lane];
  float ax = yk.x + sn * bf_lo(t0);
  float ay = yk.y + sn * bf_hi(t0);
  int i = e0;
  for (; i + 4 <= e1; i += 4){
    unsigned q0 = csr[i], q1 = csr[i+1], q2 = csr[i+2], q3 = csr[i+3];
    float w0 = h16(q0), w1 = h16(q1), w2 = h16(q2), w3 = h16(q3);
    unsigned v0 = tinb[(size_t)(q0 & 0xFFFFu) * 64 + lane];
    unsigned v1 = tinb[(size_t)(q1 & 0xFFFFu) * 64 + lane];
    unsigned v2 = tinb[(size_t)(q2 & 0xFFFFu) * 64 + lane];
    unsigned v3 = tinb[(size_t)(q3 & 0xFFFFu) * 64 + lane];
    ax += w0 * bf_lo(v0); ay += w0 * bf_hi(v0);
    ax += w1 * bf_lo(v1); ay += w1 * bf_hi(v1);
    ax += w2 * bf_lo(v2); ay += w2 * bf_hi(v2);
    ax += w3 * bf_lo(v3); ay += w3 * bf_hi(v3);
  }
  for (; i < e1; ++i){
    unsigned q = csr[i];
    float w = h16(q);
    unsigned v = tinb[(size_t)(q & 0xFFFFu) * 64 + lane];
    ax += w * bf_lo(v); ay += w * bf_hi(v);
  }
  if (wantf){
    float2 r; r.x = ax; r.y = ay;
    ((float2*)toutf)[(size_t)node * 64 + lane] = r;
  } else {
    toutb[(size_t)node * 64 + lane] = pack_rtne(ax, ay);
  }
}

// ---------------- relu + split + LDS-transpose bf16 pack ----------------

__global__ __launch_bounds__(256) void relu_trans_kernel(const float* __restrict__ u,
    float* __restrict__ emb, float* __restrict__ emb_a, short* __restrict__ embBT, int n){
  __shared__ short lds[128 * 72];
  int t = threadIdx.x;
  int node0 = blockIdx.x * 64;
  int nl = t >> 2;
  int f0 = (t & 3) * 32;
  int node = node0 + nl;
  if (node < n){
    const f32x4* up = (const f32x4*)(u + (size_t)node * 128 + f0);
    float* dst = (f0 < 64) ? (emb + (size_t)node * 64 + f0)
                           : (emb_a + (size_t)node * 64 + (f0 - 64));
    #pragma unroll
    for (int j4 = 0; j4 < 8; ++j4){
      f32x4 v = up[j4];
      #pragma unroll
      for (int e = 0; e < 4; ++e){
        float x = v[e] > 0.0f ? v[e] : 0.0f;
        v[e] = x;
        lds[(f0 + j4 * 4 + e) * 72 + nl] = f2bf(x);
      }
      ((f32x4*)dst)[j4] = v;
    }
  }
  __syncthreads();
  int f = t >> 1, c0 = (t & 1) * 32;
  short* op = embBT + (size_t)f * n + node0 + c0;
  const short* lp = lds + f * 72 + c0;
  if (node0 + 64 <= n){
    #pragma unroll
    for (int j = 0; j < 4; ++j)
      *(s16x8*)(op + j * 8) = *(const s16x8*)(lp + j * 8);
  } else {
    for (int j = 0; j < 32; ++j)
      if (node0 + c0 + j < n) op[j] = lp[j];
  }
}

// ---------------- readout GEMM: vsum[ks][n][128] partial = mask @ embBT^T ----------------
// global_load_lds double-buffered, counted-vmcnt pipeline, chunk-XOR swizzle
// via pre-swizzled global source + swizzled ds_read (rule 21). Tile 64x128xBK32.

__global__ __launch_bounds__(256, 4) void readout_kernel(const float* __restrict__ mask,
    const short* __restrict__ embBT, float* __restrict__ vsum, int n){
  __shared__ float Ab[2][64][32];   // logical [row][k], chunk-swizzled physically
  __shared__ short Bb[2][128][32];
  int t = threadIdx.x;
  int w = t >> 6, l = t & 63, lr = l & 15, g = l >> 4;
  int row0 = blockIdx.x * 64;
  int ks = blockIdx.y;

  int steps_total = (n + 31) >> 5;               // 313
  int per = steps_total / KSPLIT, rem = steps_total % KSPLIT;
  int sbeg = ks * per + (ks < rem ? ks : rem);
  int scnt = per + (ks < rem ? 1 : 0);
  bool tail = ((sbeg + scnt) == steps_total) && ((n & 31) != 0);
  int nf = scnt - (tail ? 1 : 0);
  int kb0 = sbeg << 5;

  // staging sources: linear LDS dest (lane*16B), source chunk pre-XOR'd
  int arow = row0 + w * 16 + (l >> 3);
  int aswz = ((l & 7) ^ ((l >> 3) & 7)) << 2;                 // float offset
  const float* asrc0 = mask + (size_t)min(arow,     n - 1) * n + aswz;
  const float* asrc1 = mask + (size_t)min(arow + 8, n - 1) * n + aswz;
  int bcol = w * 32 + (l >> 2);
  int bswz = ((l & 3) ^ ((l >> 3) & 3)) << 3;                 // short offset
  const short* bsrc0 = embBT + (size_t)bcol * n + bswz;
  const short* bsrc1 = embBT + (size_t)(bcol + 16) * n + bswz;

  #define GLDS(gp, lp) __builtin_amdgcn_global_load_lds( \
      (const __attribute__((address_space(1))) void*)(const void*)(gp), \
      (__attribute__((address_space(3))) void*)(void*)(lp), 16, 0, 0)
  #define STAGE(kb, bi) do{ \
    GLDS(asrc0 + (kb), &Ab[bi][w * 16     ][0]); \
    GLDS(asrc1 + (kb), &Ab[bi][w * 16 +  8][0]); \
    GLDS(bsrc0 + (kb), &Bb[bi][w * 32     ][0]); \
    GLDS(bsrc1 + (kb), &Bb[bi][w * 32 + 16][0]); \
  }while(0)

  f32x4 acc[8];
  #pragma unroll
  for (int ct = 0; ct < 8; ++ct) acc[ct] = (f32x4){0,0,0,0};

  if (nf > 0) STAGE(kb0, 0);
  if (nf > 1) STAGE(kb0 + 32, 1);

  for (int s = 0; s < nf; ++s){
    if (s + 1 < nf) asm volatile("s_waitcnt vmcnt(4)" ::: "memory");
    else            asm volatile("s_waitcnt vmcnt(0)" ::: "memory");
    __builtin_amdgcn_s_barrier();
    int cur = s & 1;
    f32x4 x0 = *(const f32x4*)&Ab[cur][w * 16 + lr][((2 * g)     ^ (lr & 7)) << 2];
    f32x4 x1 = *(const f32x4*)&Ab[cur][w * 16 + lr][((2 * g + 1) ^ (lr & 7)) << 2];
    FragU af;
    af.u[0] = pack_trunc(x0[0], x0[1]); af.u[1] = pack_trunc(x0[2], x0[3]);
    af.u[2] = pack_trunc(x1[0], x1[1]); af.u[3] = pack_trunc(x1[2], x1[3]);
    #pragma unroll
    for (int ct = 0; ct < 8; ++ct){
      s16x8 bf = *(const s16x8*)&Bb[cur][ct * 16 + lr][(g ^ ((lr >> 1) & 3)) << 3];
      acc[ct] = __builtin_amdgcn_mfma_f32_16x16x32_bf16(af.s, bf, acc[ct], 0, 0, 0);
    }
    asm volatile("s_waitcnt lgkmcnt(0)" ::: "memory");
    __builtin_amdgcn_s_barrier();
    if (s + 2 < nf) STAGE(kb0 + (s + 2) * 32, cur);
  }
  #undef STAGE
  #undef GLDS

  if (tail){
    int kb = kb0 + nf * 32;
    int kleft = n - kb;                          // 16
    FragU af; af.u = (u32x4){0,0,0,0};
    const s16x8 bz = {0,0,0,0,0,0,0,0};
    s16x8 bf[8];
    #pragma unroll
    for (int ct = 0; ct < 8; ++ct) bf[ct] = bz;
    int r = row0 + w * 16 + lr;
    if (g * 8 < kleft){
      if (r < n){
        const f32x4* p = (const f32x4*)(mask + (size_t)r * n + kb + g * 8);
        f32x4 r0 = p[0], r1 = p[1];
        af.u[0] = pack_trunc(r0[0], r0[1]); af.u[1] = pack_trunc(r0[2], r0[3]);
        af.u[2] = pack_trunc(r1[0], r1[1]); af.u[3] = pack_trunc(r1[2], r1[3]);
      }
      #pragma unroll
      for (int ct = 0; ct < 8; ++ct)
        bf[ct] = *(const s16x8*)(embBT + (size_t)(ct * 16 + lr) * n + kb + g * 8);
    }
    #pragma unroll
    for (int ct = 0; ct < 8; ++ct)
      acc[ct] = __builtin_amdgcn_mfma_f32_16x16x32_bf16(af.s, bf[ct], acc[ct], 0, 0, 0);
  }

  float* vs = vsum + (size_t)ks * n * 128;
  int rbase = row0 + w * 16;
  #pragma unroll
  for (int ct = 0; ct < 8; ++ct)
    #pragma unroll
    for (int i = 0; i < 4; ++i){
      int gr = rbase + g * 4 + i;
      if (gr < n) vs[(size_t)gr * 128 + ct * 16 + lr] = acc[ct][i];
    }
}

// ---------------- fused: g = sigmoid(v/||v||) (K-split sum) + bilinear discriminator ----------------

__global__ __launch_bounds__(256) void gnorm_disc_kernel(const float* __restrict__ vsum,
    const float* __restrict__ emb, const float* __restrict__ emb_a,
    const float* __restrict__ Wb, const float* __restrict__ bptr,
    float* __restrict__ ret, float* __restrict__ reta, int n){
  __shared__ float Wl[64][65];
  int t = threadIdx.x;
  for (int i = t; i < 4096; i += 256) Wl[i >> 6][i & 63] = Wb[i];
  __syncthreads();
  int wid = t >> 6, lane = t & 63;
  int node = blockIdx.x * 4 + wid;
  if (node >= n) return;

  size_t stride = (size_t)n * 128;
  float v1 = 0.0f, v2 = 0.0f;
  #pragma unroll
  for (int ks = 0; ks < KSPLIT; ++ks){
    v1 += vsum[ks * stride + (size_t)node * 128 + lane];
    v2 += vsum[ks * stride + (size_t)node * 128 + 64 + lane];
  }
  float s1 = v1 * v1, s2 = v2 * v2;
  for (int off = 32; off >= 1; off >>= 1){
    s1 += __shfl_xor(s1, off);
    s2 += __shfl_xor(s2, off);
  }
  float i1 = v1 / fmaxf(sqrtf(s1), 1e-12f);
  float i2 = v2 / fmaxf(sqrtf(s2), 1e-12f);
  float g1 = 1.0f / (1.0f + expf(-i1));
  float g2 = 1.0f / (1.0f + expf(-i2));

  float e1 = emb[(size_t)node * 64 + lane];
  float e2 = emb_a[(size_t)node * 64 + lane];
  float u1 = 0.0f, u2 = 0.0f;
  for (int e = 0; e < 64; ++e){
    float wv = Wl[lane][e];
    u1 += wv * __shfl(g1, e);
    u2 += wv * __shfl(g2, e);
  }
  float p1 = e1 * u1, p2 = e2 * u1, p3 = e2 * u2, p4 = e1 * u2;
  for (int off = 32; off >= 1; off >>= 1){
    p1 += __shfl_xor(p1, off); p2 += __shfl_xor(p2, off);
    p3 += __shfl_xor(p3, off); p4 += __shfl_xor(p4, off);
  }
  if (lane == 0){
    float b = bptr[0];
    ret[(size_t)node * 2 + 0]  = p1 + b;
    ret[(size_t)node * 2 + 1]  = p2 + b;
    reta[(size_t)node * 2 + 0] = p3 + b;
    reta[(size_t)node * 2 + 1] = p4 + b;
  }
}

// ---------------- launch ----------------

extern "C" void kernel_launch(void* const* d_in, const int* in_sizes, int n_in,
                              void* d_out, int out_size, void* d_ws, size_t ws_size,
                              hipStream_t stream) {
  const float* feat   = (const float*)d_in[0];
  const float* feat_a = (const float*)d_in[1];
  const int*   ei     = (const int*)d_in[2];
  const float* mask   = (const float*)d_in[3];
  const float* W      = (const float*)d_in[4];
  const float* Wb     = (const float*)d_in[5];
  const float* bsc    = (const float*)d_in[6];
  const int n = in_sizes[0] / F_IN;      // 10000
  const int E = in_sizes[2] / 2;         // 640000
  const size_t sl128 = (size_t)n * 128;

  float* out  = (float*)d_out;
  float* ret  = out + (size_t)n * F_OUT;
  float* reta = ret + (size_t)n * 2;

  char* wsb = (char*)d_ws;
  size_t off = 0;
  #define WSALLOC(ptr, T, cnt) T* ptr = (T*)(wsb + off); off = (off + sizeof(T)*(size_t)(cnt) + 255) & ~(size_t)255
  WSALLOC(deg, int, n);
  WSALLOC(counts, int, n);
  WSALLOC(offs, int, n + 1);
  WSALLOC(dis, float, n);
  WSALLOC(selfnorm, float, n);
  WSALLOC(csr, unsigned, E);
  WSALLOC(blkcnt, int, (size_t)HBLK * n);
  WSALLOC(blkbase, int, (size_t)HBLK * n);
  WSALLOC(WT, short, 5 * 64 * 256);
  WSALLOC(Yc, float, sl128 * 5);
  WSALLOC(t0bf, unsigned, (size_t)n * 64);
  WSALLOC(tb0, unsigned, (size_t)n * 64);
  WSALLOC(tb1, unsigned, (size_t)n * 64);
  WSALLOC(u1, float, sl128);
  WSALLOC(emb_a, float, (size_t)n * F_OUT);
  WSALLOC(embBT, short, (size_t)128 * n);
  WSALLOC(vsum, float, sl128 * KSPLIT);
  (void)ws_size; (void)n_in; (void)out_size;

  wt_zero_kernel<<<(5 * 64 * 256 + 255) / 256, 256, 0, stream>>>(W, WT, deg, counts, n);
  hist_kernel<<<HBLK, 1024, 0, stream>>>(ei, E, deg, counts, blkcnt, n);
  scan_kernel<<<1, 1024, 0, stream>>>(counts, deg, dis, selfnorm, offs, n);
  blkbase_kernel<<<(n + 255) / 256, 256, 0, stream>>>(offs, blkcnt, blkbase, n);
  fill_kernel<<<HBLK, 1024, 0, stream>>>(ei, E, dis, blkbase, csr, n);

  fgemm_kernel<<<dim3(n / 16, 2), 64, 0, stream>>>(feat, feat_a, WT, Yc, (short*)t0bf, n);

  int gb = (n + 3) / 4;
  // Horner: u = Yc4(bf16); u = Yc3 + A u; ... ; u = Yc0 + A u (f32 final)
  gather_kernel<<<gb, 256, 0, stream>>>(Yc + 3 * sl128, t0bf, offs, csr, selfnorm, tb0, (float*)0, n, 0);
  gather_kernel<<<gb, 256, 0, stream>>>(Yc + 2 * sl128, tb0,  offs, csr, selfnorm, tb1, (float*)0, n, 0);
  gather_kernel<<<gb, 256, 0, stream>>>(Yc + 1 * sl128, tb1,  offs, csr, selfnorm, tb0, (float*)0, n, 0);
  gather_kernel<<<gb, 256, 0, stream>>>(Yc + 0 * sl128, tb0,  offs, csr, selfnorm, (unsigned*)0, u1, n, 1);
  relu_trans_kernel<<<(n + 63) / 64, 256, 0, stream>>>(u1, out, emb_a, embBT, n);

  readout_kernel<<<dim3((n + 63) / 64, KSPLIT), 256, 0, stream>>>(mask, embBT, vsum, n);
  gnorm_disc_kernel<<<gb, 256, 0, stream>>>(vsum, out, emb_a, Wb, bsc, ret, reta, n);
}